// Round 1
// baseline (377.453 us; speedup 1.0000x reference)
//
#include <hip/hip_runtime.h>
#include <hip/hip_bf16.h>

#define NFEAT 256
#define NQ    64          // NFEAT/4 float4 quads
#define SPLIT 32          // row-splits per segment for the stats pass

// ---------------------------------------------------------------------------
// Kernel 0: exclusive prefix scan of the 128 segment lengths -> offsets[B+1]
// ---------------------------------------------------------------------------
__global__ void k_offsets(const int* __restrict__ lengths, int* __restrict__ off, int B) {
    if (threadIdx.x == 0) {
        int acc = 0;
        for (int i = 0; i < B; ++i) { off[i] = acc; acc += lengths[i]; }
        off[B] = acc;
    }
}

// ---------------------------------------------------------------------------
// Kernel 1: per-(segment, split) partial sum and sum-of-squares per feature.
// Block = 256 threads = 4 row-lanes x 64 feature-quads (float4 per thread).
// ---------------------------------------------------------------------------
__global__ __launch_bounds__(256) void k_partial(const float* __restrict__ x,
                                                 const int* __restrict__ off,
                                                 float* __restrict__ psum,
                                                 float* __restrict__ psumsq) {
    const int bid = blockIdx.x;
    const int seg = bid / SPLIT;
    const int s   = bid % SPLIT;
    const int start = off[seg];
    const int end   = off[seg + 1];
    const int len   = end - start;
    const int chunk = (len + SPLIT - 1) / SPLIT;
    const int r0 = start + s * chunk;
    const int r1 = min(r0 + chunk, end);

    const int rl = threadIdx.x >> 6;   // 0..3 row lane
    const int c  = threadIdx.x & 63;   // feature quad

    float4 sum = make_float4(0.f, 0.f, 0.f, 0.f);
    float4 sq  = make_float4(0.f, 0.f, 0.f, 0.f);

    const float4* x4 = reinterpret_cast<const float4*>(x);
    for (int r = r0 + rl; r < r1; r += 4) {
        float4 v = x4[(size_t)r * NQ + c];
        sum.x += v.x; sum.y += v.y; sum.z += v.z; sum.w += v.w;
        sq.x  += v.x * v.x; sq.y += v.y * v.y; sq.z += v.z * v.z; sq.w += v.w * v.w;
    }

    __shared__ float4 lsum[4][NQ];
    __shared__ float4 lsq[4][NQ];
    lsum[rl][c] = sum;
    lsq[rl][c]  = sq;
    __syncthreads();

    if (rl == 0) {
        float4 a0 = lsum[0][c], a1 = lsum[1][c], a2 = lsum[2][c], a3 = lsum[3][c];
        float4 q0 = lsq[0][c],  q1 = lsq[1][c],  q2 = lsq[2][c],  q3 = lsq[3][c];
        float4 ts, tq;
        ts.x = a0.x + a1.x + a2.x + a3.x;
        ts.y = a0.y + a1.y + a2.y + a3.y;
        ts.z = a0.z + a1.z + a2.z + a3.z;
        ts.w = a0.w + a1.w + a2.w + a3.w;
        tq.x = q0.x + q1.x + q2.x + q3.x;
        tq.y = q0.y + q1.y + q2.y + q3.y;
        tq.z = q0.z + q1.z + q2.z + q3.z;
        tq.w = q0.w + q1.w + q2.w + q3.w;
        reinterpret_cast<float4*>(psum)[(size_t)bid * NQ + c]   = ts;
        reinterpret_cast<float4*>(psumsq)[(size_t)bid * NQ + c] = tq;
    }
}

// ---------------------------------------------------------------------------
// Kernel 2: reduce the SPLIT partials per segment -> mean, rstd  [B][F]
// ---------------------------------------------------------------------------
__global__ __launch_bounds__(256) void k_finalize(const float* __restrict__ psum,
                                                  const float* __restrict__ psumsq,
                                                  const int* __restrict__ off,
                                                  float* __restrict__ mean,
                                                  float* __restrict__ rstd) {
    const int seg = blockIdx.x;
    const int f   = threadIdx.x;
    const float cnt = (float)(off[seg + 1] - off[seg]);
    float s = 0.f, q = 0.f;
    for (int k = 0; k < SPLIT; ++k) {
        s += psum[((size_t)seg * SPLIT + k) * NFEAT + f];
        q += psumsq[((size_t)seg * SPLIT + k) * NFEAT + f];
    }
    const float m = s / cnt;
    const float v = fmaxf(q / cnt - m * m, 0.f);
    mean[(size_t)seg * NFEAT + f] = m;
    rstd[(size_t)seg * NFEAT + f] = rsqrtf(v + 1e-5f);
}

// ---------------------------------------------------------------------------
// Kernel 3: normalize. Grid-stride over float4 items; seg via binary search
// on LDS-cached offsets; weight/bias cached in LDS.
// ---------------------------------------------------------------------------
__global__ __launch_bounds__(256) void k_norm(const float* __restrict__ x,
                                              const int* __restrict__ off,
                                              const float* __restrict__ mean,
                                              const float* __restrict__ rstd,
                                              const float* __restrict__ weight,
                                              const float* __restrict__ bias,
                                              float* __restrict__ out,
                                              int B, long nItems) {
    __shared__ int    soff[129];
    __shared__ float4 sw[NQ];
    __shared__ float4 sb[NQ];
    for (int i = threadIdx.x; i <= B; i += blockDim.x) soff[i] = off[i];
    if (threadIdx.x < NQ) {
        sw[threadIdx.x] = reinterpret_cast<const float4*>(weight)[threadIdx.x];
        sb[threadIdx.x] = reinterpret_cast<const float4*>(bias)[threadIdx.x];
    }
    __syncthreads();

    const float4* x4 = reinterpret_cast<const float4*>(x);
    const float4* m4 = reinterpret_cast<const float4*>(mean);
    const float4* r4 = reinterpret_cast<const float4*>(rstd);
    float4* o4 = reinterpret_cast<float4*>(out);

    const long stride = (long)gridDim.x * blockDim.x;
    for (long idx = (long)blockIdx.x * blockDim.x + threadIdx.x; idx < nItems; idx += stride) {
        const int row = (int)(idx >> 6);
        const int q   = (int)(idx & 63);
        // binary search: soff[lo] <= row < soff[hi]
        int lo = 0, hi = B;
        while (hi - lo > 1) {
            int mid = (lo + hi) >> 1;
            if (soff[mid] <= row) lo = mid; else hi = mid;
        }
        const int seg = lo;

        float4 v = x4[idx];
        float4 m = m4[(size_t)seg * NQ + q];
        float4 r = r4[(size_t)seg * NQ + q];
        float4 w = sw[q];
        float4 b = sb[q];
        float4 o;
        o.x = (v.x - m.x) * r.x * w.x + b.x;
        o.y = (v.y - m.y) * r.y * w.y + b.y;
        o.z = (v.z - m.z) * r.z * w.z + b.z;
        o.w = (v.w - m.w) * r.w * w.w + b.w;
        o4[idx] = o;
    }
}

extern "C" void kernel_launch(void* const* d_in, const int* in_sizes, int n_in,
                              void* d_out, int out_size, void* d_ws, size_t ws_size,
                              hipStream_t stream) {
    const float* x       = (const float*)d_in[0];
    const int*   lengths = (const int*)d_in[1];
    const float* weight  = (const float*)d_in[2];
    const float* bias    = (const float*)d_in[3];
    float*       out     = (float*)d_out;

    const int B = in_sizes[1];               // 128 segments
    const int N = in_sizes[0] / NFEAT;       // 524288 rows
    const long nItems = (long)N * NQ;        // float4 items

    // ws layout
    char* ws = (char*)d_ws;
    int*   off    = (int*)ws;                                    // (B+1) ints
    float* mean   = (float*)(ws + 1024);                         // B*F floats
    float* rstd   = (float*)(ws + 1024 + (size_t)B * NFEAT * 4); // B*F floats
    float* psum   = (float*)(ws + 1024 + (size_t)2 * B * NFEAT * 4);
    float* psumsq = psum + (size_t)B * SPLIT * NFEAT;

    k_offsets<<<1, 64, 0, stream>>>(lengths, off, B);
    k_partial<<<B * SPLIT, 256, 0, stream>>>(x, off, psum, psumsq);
    k_finalize<<<B, NFEAT, 0, stream>>>(psum, psumsq, off, mean, rstd);
    k_norm<<<4096, 256, 0, stream>>>(x, off, mean, rstd, weight, bias, out, B, nItems);
}